// Round 11
// baseline (519.511 us; speedup 1.0000x reference)
//
#include <hip/hip_runtime.h>
#include <hip/hip_bf16.h>
#include <math.h>

#define PN0 131072
#define PN1 16384
#define PN2 4096
#define PK  8

typedef __attribute__((ext_vector_type(8))) short short8;
typedef __attribute__((ext_vector_type(4))) float f32x4;

__device__ __forceinline__ unsigned pkbf2(float a, float b) {
  unsigned ua = __float_as_uint(a); ua = (ua + 0x7FFFu + ((ua >> 16) & 1u)) >> 16;
  unsigned ub = __float_as_uint(b); ub = (ub + 0x7FFFu + ((ub >> 16) & 1u)) >> 16;
  return ua | (ub << 16);
}
__device__ __forceinline__ unsigned short bf16r(float a) {
  unsigned ua = __float_as_uint(a);
  return (unsigned short)((ua + 0x7FFFu + ((ua >> 16) & 1u)) >> 16);
}
__device__ __forceinline__ float sigf(float x) { return 1.f / (1.f + __expf(-x)); }
__device__ __forceinline__ float tanh_fast(float x) { return 1.f - 2.f / (__expf(2.f * x) + 1.f); }
__device__ __forceinline__ float gelu_f(float v) {
  return 0.5f * v * (1.f + erff(v * 0.70710678118654752f));
}
// permuted bf16 column position for logical col n (within its 32-block)
__device__ __forceinline__ int permc(int n) {
  return (n & ~31) + (((n >> 2) & 3) * 8) + (((n >> 4) & 1) * 4) + (n & 3);
}

__device__ __forceinline__ void gload16(const void* g, void* l) {
  __builtin_amdgcn_global_load_lds(
      (const __attribute__((address_space(1))) void*)g,
      (__attribute__((address_space(3))) void*)l, 16, 0, 0);
}

// ================= fused prep (one dispatch) =================
__device__ __forceinline__ void dev_cvt_perm(int t, unsigned short* dst,
                                             const float* src) {
  int row = t >> 3, c0 = (t & 7) * 32;
  const float* s = src + (size_t)row * 256 + c0;
  unsigned short* d = dst + (size_t)row * 256 + c0;
  float f[32];
#pragma unroll
  for (int i = 0; i < 8; ++i) *(float4*)&f[i * 4] = *(const float4*)(s + i * 4);
#pragma unroll
  for (int q = 0; q < 4; ++q) {
    uint4 u;
    u.x = pkbf2(f[4 * q + 0], f[4 * q + 1]);
    u.y = pkbf2(f[4 * q + 2], f[4 * q + 3]);
    u.z = pkbf2(f[16 + 4 * q + 0], f[16 + 4 * q + 1]);
    u.w = pkbf2(f[16 + 4 * q + 2], f[16 + 4 * q + 3]);
    *(uint4*)(d + q * 8) = u;
  }
}

// gated weight pack, LOGICAL-LINEAR (register-direct B consumer in step kernels)
__device__ __forceinline__ void dev_pack_w_lin(int t, unsigned short* dst,
                                               const float* Wih, const float* Whh) {
  int e = t & 7, q = (t >> 3) & 3, row = (t >> 5) & 127;
  int kc = (t >> 12) & 15, tn = t >> 16;
  int k = kc * 32 + 16 * (e >> 2) + 4 * q + (e & 3);
  int hc = tn * 32 + ((row >> 6) << 4) + (row & 15);
  int g = (row >> 4) & 3;
  int n = g * 256 + hc;
  float v = (k < 256) ? Wih[(size_t)n * 256 + k] : Whh[(size_t)n * 256 + (k - 256)];
  dst[t] = bf16r(v);
}

// plain weight pack (combine/MLP), KEEPS the LDS-bank swizzle (LDS consumers)
__device__ __forceinline__ void dev_pack_plain(int t, unsigned short* dst,
                                               const float* A, const float* B, int nkc) {
  int e = t & 7, slot = (t >> 3) & 3, row = (t >> 5) & 127;
  int rest = t >> 12;
  int kc = rest % nkc, tn = rest / nkc;
  int q = slot ^ ((row >> 1) & 3);
  int k = kc * 32 + 16 * (e >> 2) + 4 * q + (e & 3);
  int n = tn * 128 + row;
  float v = (k < 256) ? A[(size_t)n * 256 + k] : B[(size_t)n * 256 + (k - 256)];
  dst[t] = bf16r(v);
}

__global__ __launch_bounds__(256) void prep_kernel(
    unsigned short* __restrict__ h0b, const float* __restrict__ h0,
    unsigned short* __restrict__ pB1, const float* __restrict__ Wih1, const float* __restrict__ Whh1,
    unsigned short* __restrict__ pB2, const float* __restrict__ Wih2, const float* __restrict__ Whh2,
    unsigned short* __restrict__ pC1, const float* __restrict__ Ws1, const float* __restrict__ Wn1,
    unsigned short* __restrict__ pC2, const float* __restrict__ Ws2, const float* __restrict__ Wn2,
    unsigned short* __restrict__ pM, const float* __restrict__ W1,
    float* __restrict__ bcat1, const float* __restrict__ bih1, const float* __restrict__ bhh1,
    float* __restrict__ bcat2, const float* __restrict__ bih2, const float* __restrict__ bhh2)
{
  const int b = blockIdx.x;
  const int tid = threadIdx.x;
  if (b < 4096) {
    dev_cvt_perm(b * 256 + tid, h0b, h0);
  } else if (b < 6144) {
    dev_pack_w_lin((b - 4096) * 256 + tid, pB1, Wih1, Whh1);
  } else if (b < 8192) {
    dev_pack_w_lin((b - 6144) * 256 + tid, pB2, Wih2, Whh2);
  } else if (b < 8704) {
    dev_pack_plain((b - 8192) * 256 + tid, pC1, Ws1, Wn1, 16);
  } else if (b < 9216) {
    dev_pack_plain((b - 8704) * 256 + tid, pC2, Ws2, Wn2, 16);
  } else if (b < 9472) {
    dev_pack_plain((b - 9216) * 256 + tid, pM, W1, W1, 8);
  } else {
    int i = (b - 9472) * 256 + tid;
    if (i < 1024) bcat1[i] = bih1[i] + bhh1[i];
    else          bcat2[i - 1024] = bih2[i - 1024] + bhh2[i - 1024];
  }
}

// ================= MFMA LSTM step: A via LDS (2-buf gload_lds), B register-direct =================
// MI=4: 128x128 tile, grid (M/128, 8).  MI=2: 64x128 tile, grid (M/64, 8).
// B fragments: contiguous 16B per lane in the logical-linear pack; a wave's 4 loads
// are coalesced 1KB bursts, L2-hot (shared by all bx blocks). A keeps the verified
// swizzled-source gload_lds staging.
template<int MI>
__global__ __launch_bounds__(256) void lstm_step_t(
    const unsigned short* __restrict__ xb,
    const int* __restrict__ idx, int t,
    const unsigned short* __restrict__ hb_in,
    const unsigned short* __restrict__ packW,   // logical-linear gated pack
    const float* __restrict__ bcat,
    float* __restrict__ cbuf,
    unsigned short* __restrict__ hb_out,
    int first)
{
  __shared__ short As[2][MI * 1024];

  const int tid = threadIdx.x;
  const int l = tid & 63;
  const int w = tid >> 6;
  const int m0 = blockIdx.x * (MI * 32);
  const int tn = blockIdx.y;
  const int wm = w >> 1, wn = w & 1;

  const int q = (l & 3) ^ ((l >> 3) & 3);
  const int r0 = w * (MI * 8) + (l >> 2);
  const int m_a = m0 + r0;
  const unsigned short* xp0 = xb + (size_t)idx[(size_t)m_a * PK + t] * 256 + 8 * q;
  const unsigned short* hp0 = hb_in + (size_t)m_a * 256 + 8 * q;
  const unsigned short* xp1 = nullptr;
  const unsigned short* hp1 = nullptr;
  if constexpr (MI == 4) {
    const int m_b = m_a + 16;
    xp1 = xb + (size_t)idx[(size_t)m_b * PK + t] * 256 + 8 * q;
    hp1 = hb_in + (size_t)m_b * 256 + 8 * q;
  }

  const int lr = l & 15;
  const int lq = l >> 4;
  const int slot_r = (lq ^ ((l >> 1) & 3)) * 8;

  // B fragment base pointers (register-direct, logical-linear pack)
  const unsigned short* br[4];
#pragma unroll
  for (int ni = 0; ni < 4; ++ni) {
    const int nrow = wn * 64 + ni * 16 + lr;
    br[ni] = packW + (size_t)tn * 65536 + (size_t)nrow * 32 + lq * 8;
  }

  f32x4 acc[MI][4];
#pragma unroll
  for (int mi = 0; mi < MI; ++mi)
#pragma unroll
    for (int ni = 0; ni < 4; ++ni) acc[mi][ni] = (f32x4)(0.f);

  auto STAGE = [&](int buf, int kc) {
    short* Ad = &As[buf][0];
    const unsigned short* s0 = (kc < 8) ? xp0 + kc * 32 : hp0 + (kc - 8) * 32;
    gload16(s0, Ad + w * (MI * 256));
    if constexpr (MI == 4) {
      const unsigned short* s1 = (kc < 8) ? xp1 + kc * 32 : hp1 + (kc - 8) * 32;
      gload16(s1, Ad + w * 1024 + 512);
    }
  };

  auto COMPUTE = [&](int buf, int kc) {
    short8 af[MI], bf[4];
#pragma unroll
    for (int ni = 0; ni < 4; ++ni)
      bf[ni] = *(const short8*)(br[ni] + (size_t)kc * 4096);
#pragma unroll
    for (int mi = 0; mi < MI; ++mi)
      af[mi] = *(const short8*)&As[buf][(wm * (MI * 16) + mi * 16 + lr) * 32 + slot_r];
#pragma unroll
    for (int mi = 0; mi < MI; ++mi)
#pragma unroll
      for (int ni = 0; ni < 4; ++ni)
        acc[mi][ni] = __builtin_amdgcn_mfma_f32_16x16x32_bf16(af[mi], bf[ni], acc[mi][ni], 0, 0, 0);
  };

  const int NK = first ? 8 : 16;
  STAGE(0, 0);
  __syncthreads();
  for (int kc = 0; kc < NK; ++kc) {
    const int cur = kc & 1;
    if (kc + 1 < NK) STAGE(cur ^ 1, kc + 1);
    COMPUTE(cur, kc);
    __syncthreads();
  }

  // epilogue: gates -> c,h
  const int hc = tn * 32 + wn * 16 + lr;
  const float bi = bcat[hc], bff = bcat[256 + hc], bg = bcat[512 + hc], bo = bcat[768 + hc];
  const int hpos = permc(hc);
#pragma unroll
  for (int mi = 0; mi < MI; ++mi) {
#pragma unroll
    for (int r = 0; r < 4; ++r) {
      const int m = m0 + wm * (MI * 16) + mi * 16 + lq * 4 + r;
      const size_t off = (size_t)m * 256;
      const float zi = acc[mi][0][r] + bi;
      const float zf = acc[mi][1][r] + bff;
      const float zg = acc[mi][2][r] + bg;
      const float zo = acc[mi][3][r] + bo;
      const float cp = first ? 0.f : cbuf[off + hc];
      const float cn = sigf(zf) * cp + sigf(zi) * tanh_fast(zg);
      const float hn = sigf(zo) * tanh_fast(cn);
      cbuf[off + hc] = cn;
      hb_out[off + hpos] = bf16r(hn);
    }
  }
}

// ================= fused combine GEMM + GELU + LN (+BN), bf16-permuted out =================
__global__ __launch_bounds__(256) void combine_ln_kernel(
    const unsigned short* __restrict__ selfb,
    const unsigned short* __restrict__ neighb,
    const unsigned short* __restrict__ packW,   // 2 tiles x 16 kc x 128 x 32 (pre-swizzled)
    const float* __restrict__ bias,
    unsigned short* __restrict__ outb,
    const float* __restrict__ g, const float* __restrict__ b,
    const float* bnm, const float* bnv, const float* bng, const float* bnb,
    int do_bn)
{
  __shared__ short As[2][1024];     // 32 rows x 32 k
  __shared__ short Bs[2][8192];     // 256 n x 32 k

  const int tid = threadIdx.x;
  const int l = tid & 63;
  const int w = tid >> 6;
  const int m0 = blockIdx.x * 32;
  const int wm = w >> 1, wn = w & 1;

  const int q = (l & 3) ^ ((l >> 3) & 3);
  const int arow = (w & 1) * 16 + (l >> 2);
  const unsigned short* sp = selfb + (size_t)(m0 + arow) * 256 + 8 * q;
  const unsigned short* np = neighb + (size_t)(m0 + arow) * 256 + 8 * q;

  f32x4 acc[8];
#pragma unroll
  for (int ni = 0; ni < 8; ++ni) acc[ni] = (f32x4)(0.f);

  auto STAGE = [&](int buf, int kc) {
    short* Ad = &As[buf][0];
    short* Bd = &Bs[buf][0];
#pragma unroll
    for (int u = 0; u < 4; ++u) {
      const int base = w * 64 + u * 16;
      const int tile = base >> 7, r128b = base & 127;
      gload16(packW + (size_t)tile * 65536 + (size_t)kc * 4096 + (size_t)r128b * 32 + (size_t)l * 8,
              Bd + w * 2048 + u * 512);
    }
    if (w < 2) {
      const unsigned short* s0 = (kc < 8) ? sp + kc * 32 : np + (kc - 8) * 32;
      gload16(s0, Ad + w * 512);
    }
  };

  const int lr = l & 15;
  const int lq = l >> 4;
  const int slot_r = (lq ^ ((l >> 1) & 3)) * 8;

  auto COMPUTE = [&](int buf) {
    short8 af = *(const short8*)&As[buf][(wm * 16 + lr) * 32 + slot_r];
#pragma unroll
    for (int ni = 0; ni < 8; ++ni) {
      short8 bf = *(const short8*)&Bs[buf][(wn * 128 + ni * 16 + lr) * 32 + slot_r];
      acc[ni] = __builtin_amdgcn_mfma_f32_16x16x32_bf16(af, bf, acc[ni], 0, 0, 0);
    }
  };

  STAGE(0, 0);
  __syncthreads();
  for (int kc = 0; kc < 16; ++kc) {
    const int cur = kc & 1;
    if (kc + 1 < 16) STAGE(cur ^ 1, kc + 1);
    COMPUTE(cur);
    __syncthreads();
  }

  float val[8][4];
  float s[4] = {0.f, 0.f, 0.f, 0.f}, qq[4] = {0.f, 0.f, 0.f, 0.f};
#pragma unroll
  for (int ni = 0; ni < 8; ++ni) {
    const int n = wn * 128 + ni * 16 + lr;
    const float bb = bias[n];
#pragma unroll
    for (int r = 0; r < 4; ++r) {
      float v = gelu_f(acc[ni][r] + bb);
      val[ni][r] = v;
      s[r] += v;
      qq[r] += v * v;
    }
  }
#pragma unroll
  for (int off = 1; off < 16; off <<= 1) {
#pragma unroll
    for (int r = 0; r < 4; ++r) {
      s[r] += __shfl_xor(s[r], off);
      qq[r] += __shfl_xor(qq[r], off);
    }
  }
  float* sred = (float*)&As[0][0];
  __syncthreads();
  if (lr == 0) {
#pragma unroll
    for (int r = 0; r < 4; ++r) {
      const int row = wm * 16 + lq * 4 + r;
      sred[wn * 64 + row] = s[r];
      sred[wn * 64 + 32 + row] = qq[r];
    }
  }
  __syncthreads();
#pragma unroll
  for (int r = 0; r < 4; ++r) {
    const int row = wm * 16 + lq * 4 + r;
    const float S = sred[row] + sred[64 + row];
    const float Q = sred[32 + row] + sred[96 + row];
    const float mu = S * (1.f / 256.f);
    const float var = Q * (1.f / 256.f) - mu * mu;
    const float rs = rsqrtf(var + 1e-5f);
    const int m = m0 + row;
#pragma unroll
    for (int ni = 0; ni < 8; ++ni) {
      const int n = wn * 128 + ni * 16 + lr;
      float y = (val[ni][r] - mu) * rs * g[n] + b[n];
      if (do_bn) y = (y - bnm[n]) * rsqrtf(bnv[n] + 1e-5f) * bng[n] + bnb[n];
      outb[(size_t)m * 256 + permc(n)] = bf16r(y);
    }
  }
}

// ================= fused MLP (gelu) + head dot =================
__global__ __launch_bounds__(256) void mlp_head_kernel(
    const unsigned short* __restrict__ h3b,
    const unsigned short* __restrict__ packM,
    const float* __restrict__ b1,
    const float* __restrict__ W2, const float* __restrict__ b2,
    float* __restrict__ out)
{
  __shared__ short As[2][1024];
  __shared__ short Bs[2][8192];

  const int tid = threadIdx.x;
  const int l = tid & 63;
  const int w = tid >> 6;
  const int m0 = blockIdx.x * 32;
  const int wm = w >> 1, wn = w & 1;

  const int q = (l & 3) ^ ((l >> 3) & 3);
  const int arow = (w & 1) * 16 + (l >> 2);
  const unsigned short* sp = h3b + (size_t)(m0 + arow) * 256 + 8 * q;

  f32x4 acc[8];
#pragma unroll
  for (int ni = 0; ni < 8; ++ni) acc[ni] = (f32x4)(0.f);

  auto STAGE = [&](int buf, int kc) {
    short* Ad = &As[buf][0];
    short* Bd = &Bs[buf][0];
#pragma unroll
    for (int u = 0; u < 4; ++u) {
      const int base = w * 64 + u * 16;
      const int tile = base >> 7, r128b = base & 127;
      gload16(packM + (size_t)tile * 32768 + (size_t)kc * 4096 + (size_t)r128b * 32 + (size_t)l * 8,
              Bd + w * 2048 + u * 512);
    }
    if (w < 2) gload16(sp + kc * 32, Ad + w * 512);
  };

  const int lr = l & 15;
  const int lq = l >> 4;
  const int slot_r = (lq ^ ((l >> 1) & 3)) * 8;

  auto COMPUTE = [&](int buf) {
    short8 af = *(const short8*)&As[buf][(wm * 16 + lr) * 32 + slot_r];
#pragma unroll
    for (int ni = 0; ni < 8; ++ni) {
      short8 bf = *(const short8*)&Bs[buf][(wn * 128 + ni * 16 + lr) * 32 + slot_r];
      acc[ni] = __builtin_amdgcn_mfma_f32_16x16x32_bf16(af, bf, acc[ni], 0, 0, 0);
    }
  };

  STAGE(0, 0);
  __syncthreads();
  for (int kc = 0; kc < 8; ++kc) {
    const int cur = kc & 1;
    if (kc + 1 < 8) STAGE(cur ^ 1, kc + 1);
    COMPUTE(cur);
    __syncthreads();
  }

  float s[4] = {0.f, 0.f, 0.f, 0.f};
#pragma unroll
  for (int ni = 0; ni < 8; ++ni) {
    const int n = wn * 128 + ni * 16 + lr;
    const float bb = b1[n];
    const float w2 = W2[n];
#pragma unroll
    for (int r = 0; r < 4; ++r) {
      s[r] += gelu_f(acc[ni][r] + bb) * w2;
    }
  }
#pragma unroll
  for (int off = 1; off < 16; off <<= 1)
#pragma unroll
    for (int r = 0; r < 4; ++r) s[r] += __shfl_xor(s[r], off);

  float* sred = (float*)&As[0][0];
  __syncthreads();
  if (lr == 0) {
#pragma unroll
    for (int r = 0; r < 4; ++r) sred[wn * 32 + wm * 16 + lq * 4 + r] = s[r];
  }
  __syncthreads();
  if (wn == 0 && lr == 0) {
#pragma unroll
    for (int r = 0; r < 4; ++r) {
      const int row = wm * 16 + lq * 4 + r;
      out[m0 + row] = sred[row] + sred[32 + row] + b2[0];
    }
  }
}

// ================= launch =================
extern "C" void kernel_launch(void* const* d_in, const int* in_sizes, int n_in,
                              void* d_out, int out_size, void* d_ws, size_t ws_size,
                              hipStream_t stream) {
  const float* h0       = (const float*)d_in[0];
  const int*   idx0     = (const int*)  d_in[1];
  const int*   idx1     = (const int*)  d_in[2];
  const float* W_ih1    = (const float*)d_in[3];
  const float* W_hh1    = (const float*)d_in[4];
  const float* b_ih1    = (const float*)d_in[5];
  const float* b_hh1    = (const float*)d_in[6];
  const float* W_self1  = (const float*)d_in[7];
  const float* W_neigh1 = (const float*)d_in[8];
  const float* b_neigh1 = (const float*)d_in[9];
  const float* W_ih2    = (const float*)d_in[10];
  const float* W_hh2    = (const float*)d_in[11];
  const float* b_ih2    = (const float*)d_in[12];
  const float* b_hh2    = (const float*)d_in[13];
  const float* W_self2  = (const float*)d_in[14];
  const float* W_neigh2 = (const float*)d_in[15];
  const float* b_neigh2 = (const float*)d_in[16];
  const float* ln_g     = (const float*)d_in[17];
  const float* ln_b     = (const float*)d_in[18];
  const float* bn_g     = (const float*)d_in[19];
  const float* bn_b     = (const float*)d_in[20];
  const float* bn_mean  = (const float*)d_in[21];
  const float* bn_var   = (const float*)d_in[22];
  const float* W1       = (const float*)d_in[23];
  const float* b1       = (const float*)d_in[24];
  const float* W2       = (const float*)d_in[25];
  const float* b2       = (const float*)d_in[26];
  float* out = (float*)d_out;

  // ---- workspace layout (float units) ----
  float* ws = (float*)d_ws;
  unsigned short* packB1 = (unsigned short*)ws;                   // 262144 f
  unsigned short* packB2 = (unsigned short*)(ws + 262144);        // 262144 f
  unsigned short* packC1 = (unsigned short*)(ws + 524288);        // 65536 f
  unsigned short* packC2 = (unsigned short*)(ws + 589824);        // 65536 f
  unsigned short* packM  = (unsigned short*)(ws + 655360);        // 32768 f
  float* bcat1 = ws + 688128;                                     // 1024
  float* bcat2 = bcat1 + 1024;                                    // 1024
  unsigned short* h0b = (unsigned short*)(bcat2 + 1024);          // 16777216 f
  float* afterh0 = (float*)h0b + 16777216;
  unsigned short* hbA = (unsigned short*)afterh0;                 // 2097152 f
  unsigned short* hbB = (unsigned short*)(afterh0 + 2097152);     // 2097152 f
  float* cbuf = afterh0 + 4194304;                                // 4194304
  unsigned short* h1b = (unsigned short*)(cbuf + 4194304);        // 2097152 f
  unsigned short* h3b = (unsigned short*)(cbuf + 4194304 + 2097152); // 524288 f

  // ---- fused prep (1 dispatch) ----
  prep_kernel<<<9480, 256, 0, stream>>>(
      h0b, h0,
      packB1, W_ih1, W_hh1,
      packB2, W_ih2, W_hh2,
      packC1, W_self1, W_neigh1,
      packC2, W_self2, W_neigh2,
      packM, W1,
      bcat1, b_ih1, b_hh1,
      bcat2, b_ih2, b_hh2);

  // ---- layer 1 LSTM (128-row tiles, per-step) ----
  for (int t = 0; t < PK; ++t) {
    unsigned short* hin  = (t & 1) ? hbA : hbB;
    unsigned short* hout = (t & 1) ? hbB : hbA;
    lstm_step_t<4><<<dim3(PN1 / 128, 8), 256, 0, stream>>>(
        h0b, idx0, t, hin, packB1, bcat1, cbuf, hout, t == 0);
  }
  // final h = hbB (t=7 odd); combine + gelu + LN fused
  combine_ln_kernel<<<PN1 / 32, 256, 0, stream>>>(
      h0b, hbB, packC1, b_neigh1, h1b, ln_g, ln_b,
      nullptr, nullptr, nullptr, nullptr, 0);

  // ---- layer 2 LSTM (64-row tiles, per-step) ----
  for (int t = 0; t < PK; ++t) {
    unsigned short* hin  = (t & 1) ? hbA : hbB;
    unsigned short* hout = (t & 1) ? hbB : hbA;
    lstm_step_t<2><<<dim3(PN2 / 64, 8), 256, 0, stream>>>(
        h1b, idx1, t, hin, packB2, bcat2, cbuf, hout, t == 0);
  }
  combine_ln_kernel<<<PN2 / 32, 256, 0, stream>>>(
      h1b, hbB, packC2, b_neigh2, h3b, ln_g, ln_b,
      bn_mean, bn_var, bn_g, bn_b, 1);
  // MLP + head fused
  mlp_head_kernel<<<PN2 / 32, 256, 0, stream>>>(h3b, packM, b1, W2, b2, out);
}

// Round 12
// 463.120 us; speedup vs baseline: 1.1218x; 1.1218x over previous
//
#include <hip/hip_runtime.h>
#include <hip/hip_bf16.h>
#include <math.h>

#define PN0 131072
#define PN1 16384
#define PN2 4096
#define PK  8

typedef __attribute__((ext_vector_type(8))) short short8;
typedef __attribute__((ext_vector_type(4))) float f32x4;

__device__ __forceinline__ unsigned pkbf2(float a, float b) {
  unsigned ua = __float_as_uint(a); ua = (ua + 0x7FFFu + ((ua >> 16) & 1u)) >> 16;
  unsigned ub = __float_as_uint(b); ub = (ub + 0x7FFFu + ((ub >> 16) & 1u)) >> 16;
  return ua | (ub << 16);
}
__device__ __forceinline__ unsigned short bf16r(float a) {
  unsigned ua = __float_as_uint(a);
  return (unsigned short)((ua + 0x7FFFu + ((ua >> 16) & 1u)) >> 16);
}
__device__ __forceinline__ float sigf(float x) { return 1.f / (1.f + __expf(-x)); }
__device__ __forceinline__ float tanh_fast(float x) { return 1.f - 2.f / (__expf(2.f * x) + 1.f); }
__device__ __forceinline__ float gelu_f(float v) {
  return 0.5f * v * (1.f + erff(v * 0.70710678118654752f));
}
// permuted bf16 column position for logical col n (within its 32-block)
__device__ __forceinline__ int permc(int n) {
  return (n & ~31) + (((n >> 2) & 3) * 8) + (((n >> 4) & 1) * 4) + (n & 3);
}

__device__ __forceinline__ void gload16(const void* g, void* l) {
  __builtin_amdgcn_global_load_lds(
      (const __attribute__((address_space(1))) void*)g,
      (__attribute__((address_space(3))) void*)l, 16, 0, 0);
}

// ================= fused prep (one dispatch) =================
__device__ __forceinline__ void dev_cvt_perm(int t, unsigned short* dst,
                                             const float* src) {
  int row = t >> 3, c0 = (t & 7) * 32;
  const float* s = src + (size_t)row * 256 + c0;
  unsigned short* d = dst + (size_t)row * 256 + c0;
  float f[32];
#pragma unroll
  for (int i = 0; i < 8; ++i) *(float4*)&f[i * 4] = *(const float4*)(s + i * 4);
#pragma unroll
  for (int q = 0; q < 4; ++q) {
    uint4 u;
    u.x = pkbf2(f[4 * q + 0], f[4 * q + 1]);
    u.y = pkbf2(f[4 * q + 2], f[4 * q + 3]);
    u.z = pkbf2(f[16 + 4 * q + 0], f[16 + 4 * q + 1]);
    u.w = pkbf2(f[16 + 4 * q + 2], f[16 + 4 * q + 3]);
    *(uint4*)(d + q * 8) = u;
  }
}

// gated weight pack with LDS-bank swizzle (consumed by LDS-staged step kernels)
__device__ __forceinline__ void dev_pack_w(int t, unsigned short* dst,
                                           const float* Wih, const float* Whh) {
  int e = t & 7, slot = (t >> 3) & 3, row = (t >> 5) & 127;
  int kc = (t >> 12) & 15, tn = t >> 16;
  int q = slot ^ ((row >> 1) & 3);
  int k = kc * 32 + 16 * (e >> 2) + 4 * q + (e & 3);
  int hc = tn * 32 + ((row >> 6) << 4) + (row & 15);
  int g = (row >> 4) & 3;
  int n = g * 256 + hc;
  float v = (k < 256) ? Wih[(size_t)n * 256 + k] : Whh[(size_t)n * 256 + (k - 256)];
  dst[t] = bf16r(v);
}

// plain weight pack (combine/MLP), same swizzle
__device__ __forceinline__ void dev_pack_plain(int t, unsigned short* dst,
                                               const float* A, const float* B, int nkc) {
  int e = t & 7, slot = (t >> 3) & 3, row = (t >> 5) & 127;
  int rest = t >> 12;
  int kc = rest % nkc, tn = rest / nkc;
  int q = slot ^ ((row >> 1) & 3);
  int k = kc * 32 + 16 * (e >> 2) + 4 * q + (e & 3);
  int n = tn * 128 + row;
  float v = (k < 256) ? A[(size_t)n * 256 + k] : B[(size_t)n * 256 + (k - 256)];
  dst[t] = bf16r(v);
}

__global__ __launch_bounds__(256) void prep_kernel(
    unsigned short* __restrict__ h0b, const float* __restrict__ h0,
    unsigned short* __restrict__ pB1, const float* __restrict__ Wih1, const float* __restrict__ Whh1,
    unsigned short* __restrict__ pB2, const float* __restrict__ Wih2, const float* __restrict__ Whh2,
    unsigned short* __restrict__ pC1, const float* __restrict__ Ws1, const float* __restrict__ Wn1,
    unsigned short* __restrict__ pC2, const float* __restrict__ Ws2, const float* __restrict__ Wn2,
    unsigned short* __restrict__ pM, const float* __restrict__ W1,
    float* __restrict__ bcat1, const float* __restrict__ bih1, const float* __restrict__ bhh1,
    float* __restrict__ bcat2, const float* __restrict__ bih2, const float* __restrict__ bhh2)
{
  const int b = blockIdx.x;
  const int tid = threadIdx.x;
  if (b < 4096) {
    dev_cvt_perm(b * 256 + tid, h0b, h0);
  } else if (b < 6144) {
    dev_pack_w((b - 4096) * 256 + tid, pB1, Wih1, Whh1);
  } else if (b < 8192) {
    dev_pack_w((b - 6144) * 256 + tid, pB2, Wih2, Whh2);
  } else if (b < 8704) {
    dev_pack_plain((b - 8192) * 256 + tid, pC1, Ws1, Wn1, 16);
  } else if (b < 9216) {
    dev_pack_plain((b - 8704) * 256 + tid, pC2, Ws2, Wn2, 16);
  } else if (b < 9472) {
    dev_pack_plain((b - 9216) * 256 + tid, pM, W1, W1, 8);
  } else {
    int i = (b - 9472) * 256 + tid;
    if (i < 1024) bcat1[i] = bih1[i] + bhh1[i];
    else          bcat2[i - 1024] = bih2[i - 1024] + bhh2[i - 1024];
  }
}

// ================= MFMA LSTM step, LDS-staged, 2-buf (verified-best) =================
// MI=4: 128x128 tile, grid (M/128, 8).  MI=2: 64x128 tile, grid (M/64, 8).
template<int MI>
__global__ __launch_bounds__(256) void lstm_step_t(
    const unsigned short* __restrict__ xb,
    const int* __restrict__ idx, int t,
    const unsigned short* __restrict__ hb_in,
    const unsigned short* __restrict__ packW,
    const float* __restrict__ bcat,
    float* __restrict__ cbuf,
    unsigned short* __restrict__ hb_out,
    int first)
{
  __shared__ short As[2][MI * 1024];
  __shared__ short Bs[2][4096];

  const int tid = threadIdx.x;
  const int l = tid & 63;
  const int w = tid >> 6;
  const int m0 = blockIdx.x * (MI * 32);
  const int tn = blockIdx.y;
  const int wm = w >> 1, wn = w & 1;

  const int q = (l & 3) ^ ((l >> 3) & 3);
  const int r0 = w * (MI * 8) + (l >> 2);
  const int m_a = m0 + r0;
  const unsigned short* xp0 = xb + (size_t)idx[(size_t)m_a * PK + t] * 256 + 8 * q;
  const unsigned short* hp0 = hb_in + (size_t)m_a * 256 + 8 * q;
  const unsigned short* xp1 = nullptr;
  const unsigned short* hp1 = nullptr;
  if constexpr (MI == 4) {
    const int m_b = m_a + 16;
    xp1 = xb + (size_t)idx[(size_t)m_b * PK + t] * 256 + 8 * q;
    hp1 = hb_in + (size_t)m_b * 256 + 8 * q;
  }
  const unsigned short* bp = packW + (size_t)tn * 65536 + (size_t)w * 1024 + (size_t)l * 8;

  f32x4 acc[MI][4];
#pragma unroll
  for (int mi = 0; mi < MI; ++mi)
#pragma unroll
    for (int ni = 0; ni < 4; ++ni) acc[mi][ni] = (f32x4)(0.f);

  auto STAGE = [&](int buf, int kc) {
    short* Ad = &As[buf][0];
    short* Bd = &Bs[buf][0];
    gload16(bp + (size_t)kc * 4096, Bd + w * 1024);
    gload16(bp + (size_t)kc * 4096 + 512, Bd + w * 1024 + 512);
    const unsigned short* s0 = (kc < 8) ? xp0 + kc * 32 : hp0 + (kc - 8) * 32;
    gload16(s0, Ad + w * (MI * 256));
    if constexpr (MI == 4) {
      const unsigned short* s1 = (kc < 8) ? xp1 + kc * 32 : hp1 + (kc - 8) * 32;
      gload16(s1, Ad + w * 1024 + 512);
    }
  };

  const int lr = l & 15;
  const int lq = l >> 4;
  const int slot_r = (lq ^ ((l >> 1) & 3)) * 8;

  auto COMPUTE = [&](int buf) {
    short8 af[MI], bf[4];
#pragma unroll
    for (int mi = 0; mi < MI; ++mi)
      af[mi] = *(const short8*)&As[buf][(wm * (MI * 16) + mi * 16 + lr) * 32 + slot_r];
#pragma unroll
    for (int ni = 0; ni < 4; ++ni)
      bf[ni] = *(const short8*)&Bs[buf][(wn * 64 + ni * 16 + lr) * 32 + slot_r];
#pragma unroll
    for (int mi = 0; mi < MI; ++mi)
#pragma unroll
      for (int ni = 0; ni < 4; ++ni)
        acc[mi][ni] = __builtin_amdgcn_mfma_f32_16x16x32_bf16(af[mi], bf[ni], acc[mi][ni], 0, 0, 0);
  };

  const int NK = first ? 8 : 16;
  STAGE(0, 0);
  __syncthreads();
  for (int kc = 0; kc < NK; ++kc) {
    const int cur = kc & 1;
    if (kc + 1 < NK) STAGE(cur ^ 1, kc + 1);
    COMPUTE(cur);
    __syncthreads();
  }

  // epilogue: gates -> c,h
  const int hc = tn * 32 + wn * 16 + lr;
  const float bi = bcat[hc], bff = bcat[256 + hc], bg = bcat[512 + hc], bo = bcat[768 + hc];
  const int hpos = permc(hc);
#pragma unroll
  for (int mi = 0; mi < MI; ++mi) {
#pragma unroll
    for (int r = 0; r < 4; ++r) {
      const int m = m0 + wm * (MI * 16) + mi * 16 + lq * 4 + r;
      const size_t off = (size_t)m * 256;
      const float zi = acc[mi][0][r] + bi;
      const float zf = acc[mi][1][r] + bff;
      const float zg = acc[mi][2][r] + bg;
      const float zo = acc[mi][3][r] + bo;
      const float cp = first ? 0.f : cbuf[off + hc];
      const float cn = sigf(zf) * cp + sigf(zi) * tanh_fast(zg);
      const float hn = sigf(zo) * tanh_fast(cn);
      cbuf[off + hc] = cn;
      hb_out[off + hpos] = bf16r(hn);
    }
  }
}

// ================= fused combine GEMM + GELU + LN (+BN), bf16-permuted out =================
__global__ __launch_bounds__(256) void combine_ln_kernel(
    const unsigned short* __restrict__ selfb,
    const unsigned short* __restrict__ neighb,
    const unsigned short* __restrict__ packW,   // 2 tiles x 16 kc x 128 x 32 (pre-swizzled)
    const float* __restrict__ bias,
    unsigned short* __restrict__ outb,
    const float* __restrict__ g, const float* __restrict__ b,
    const float* bnm, const float* bnv, const float* bng, const float* bnb,
    int do_bn)
{
  __shared__ short As[2][1024];     // 32 rows x 32 k
  __shared__ short Bs[2][8192];     // 256 n x 32 k

  const int tid = threadIdx.x;
  const int l = tid & 63;
  const int w = tid >> 6;
  const int m0 = blockIdx.x * 32;
  const int wm = w >> 1, wn = w & 1;

  const int q = (l & 3) ^ ((l >> 3) & 3);
  const int arow = (w & 1) * 16 + (l >> 2);
  const unsigned short* sp = selfb + (size_t)(m0 + arow) * 256 + 8 * q;
  const unsigned short* np = neighb + (size_t)(m0 + arow) * 256 + 8 * q;

  f32x4 acc[8];
#pragma unroll
  for (int ni = 0; ni < 8; ++ni) acc[ni] = (f32x4)(0.f);

  auto STAGE = [&](int buf, int kc) {
    short* Ad = &As[buf][0];
    short* Bd = &Bs[buf][0];
#pragma unroll
    for (int u = 0; u < 4; ++u) {
      const int base = w * 64 + u * 16;
      const int tile = base >> 7, r128b = base & 127;
      gload16(packW + (size_t)tile * 65536 + (size_t)kc * 4096 + (size_t)r128b * 32 + (size_t)l * 8,
              Bd + w * 2048 + u * 512);
    }
    if (w < 2) {
      const unsigned short* s0 = (kc < 8) ? sp + kc * 32 : np + (kc - 8) * 32;
      gload16(s0, Ad + w * 512);
    }
  };

  const int lr = l & 15;
  const int lq = l >> 4;
  const int slot_r = (lq ^ ((l >> 1) & 3)) * 8;

  auto COMPUTE = [&](int buf) {
    short8 af = *(const short8*)&As[buf][(wm * 16 + lr) * 32 + slot_r];
#pragma unroll
    for (int ni = 0; ni < 8; ++ni) {
      short8 bf = *(const short8*)&Bs[buf][(wn * 128 + ni * 16 + lr) * 32 + slot_r];
      acc[ni] = __builtin_amdgcn_mfma_f32_16x16x32_bf16(af, bf, acc[ni], 0, 0, 0);
    }
  };

  STAGE(0, 0);
  __syncthreads();
  for (int kc = 0; kc < 16; ++kc) {
    const int cur = kc & 1;
    if (kc + 1 < 16) STAGE(cur ^ 1, kc + 1);
    COMPUTE(cur);
    __syncthreads();
  }

  float val[8][4];
  float s[4] = {0.f, 0.f, 0.f, 0.f}, qq[4] = {0.f, 0.f, 0.f, 0.f};
#pragma unroll
  for (int ni = 0; ni < 8; ++ni) {
    const int n = wn * 128 + ni * 16 + lr;
    const float bb = bias[n];
#pragma unroll
    for (int r = 0; r < 4; ++r) {
      float v = gelu_f(acc[ni][r] + bb);
      val[ni][r] = v;
      s[r] += v;
      qq[r] += v * v;
    }
  }
#pragma unroll
  for (int off = 1; off < 16; off <<= 1) {
#pragma unroll
    for (int r = 0; r < 4; ++r) {
      s[r] += __shfl_xor(s[r], off);
      qq[r] += __shfl_xor(qq[r], off);
    }
  }
  float* sred = (float*)&As[0][0];
  __syncthreads();
  if (lr == 0) {
#pragma unroll
    for (int r = 0; r < 4; ++r) {
      const int row = wm * 16 + lq * 4 + r;
      sred[wn * 64 + row] = s[r];
      sred[wn * 64 + 32 + row] = qq[r];
    }
  }
  __syncthreads();
#pragma unroll
  for (int r = 0; r < 4; ++r) {
    const int row = wm * 16 + lq * 4 + r;
    const float S = sred[row] + sred[64 + row];
    const float Q = sred[32 + row] + sred[96 + row];
    const float mu = S * (1.f / 256.f);
    const float var = Q * (1.f / 256.f) - mu * mu;
    const float rs = rsqrtf(var + 1e-5f);
    const int m = m0 + row;
#pragma unroll
    for (int ni = 0; ni < 8; ++ni) {
      const int n = wn * 128 + ni * 16 + lr;
      float y = (val[ni][r] - mu) * rs * g[n] + b[n];
      if (do_bn) y = (y - bnm[n]) * rsqrtf(bnv[n] + 1e-5f) * bng[n] + bnb[n];
      outb[(size_t)m * 256 + permc(n)] = bf16r(y);
    }
  }
}

// ================= fused MLP (gelu) + head dot =================
__global__ __launch_bounds__(256) void mlp_head_kernel(
    const unsigned short* __restrict__ h3b,
    const unsigned short* __restrict__ packM,
    const float* __restrict__ b1,
    const float* __restrict__ W2, const float* __restrict__ b2,
    float* __restrict__ out)
{
  __shared__ short As[2][1024];
  __shared__ short Bs[2][8192];

  const int tid = threadIdx.x;
  const int l = tid & 63;
  const int w = tid >> 6;
  const int m0 = blockIdx.x * 32;
  const int wm = w >> 1, wn = w & 1;

  const int q = (l & 3) ^ ((l >> 3) & 3);
  const int arow = (w & 1) * 16 + (l >> 2);
  const unsigned short* sp = h3b + (size_t)(m0 + arow) * 256 + 8 * q;

  f32x4 acc[8];
#pragma unroll
  for (int ni = 0; ni < 8; ++ni) acc[ni] = (f32x4)(0.f);

  auto STAGE = [&](int buf, int kc) {
    short* Ad = &As[buf][0];
    short* Bd = &Bs[buf][0];
#pragma unroll
    for (int u = 0; u < 4; ++u) {
      const int base = w * 64 + u * 16;
      const int tile = base >> 7, r128b = base & 127;
      gload16(packM + (size_t)tile * 32768 + (size_t)kc * 4096 + (size_t)r128b * 32 + (size_t)l * 8,
              Bd + w * 2048 + u * 512);
    }
    if (w < 2) gload16(sp + kc * 32, Ad + w * 512);
  };

  const int lr = l & 15;
  const int lq = l >> 4;
  const int slot_r = (lq ^ ((l >> 1) & 3)) * 8;

  auto COMPUTE = [&](int buf) {
    short8 af = *(const short8*)&As[buf][(wm * 16 + lr) * 32 + slot_r];
#pragma unroll
    for (int ni = 0; ni < 8; ++ni) {
      short8 bf = *(const short8*)&Bs[buf][(wn * 128 + ni * 16 + lr) * 32 + slot_r];
      acc[ni] = __builtin_amdgcn_mfma_f32_16x16x32_bf16(af, bf, acc[ni], 0, 0, 0);
    }
  };

  STAGE(0, 0);
  __syncthreads();
  for (int kc = 0; kc < 8; ++kc) {
    const int cur = kc & 1;
    if (kc + 1 < 8) STAGE(cur ^ 1, kc + 1);
    COMPUTE(cur);
    __syncthreads();
  }

  float s[4] = {0.f, 0.f, 0.f, 0.f};
#pragma unroll
  for (int ni = 0; ni < 8; ++ni) {
    const int n = wn * 128 + ni * 16 + lr;
    const float bb = b1[n];
    const float w2 = W2[n];
#pragma unroll
    for (int r = 0; r < 4; ++r) {
      s[r] += gelu_f(acc[ni][r] + bb) * w2;
    }
  }
#pragma unroll
  for (int off = 1; off < 16; off <<= 1)
#pragma unroll
    for (int r = 0; r < 4; ++r) s[r] += __shfl_xor(s[r], off);

  float* sred = (float*)&As[0][0];
  __syncthreads();
  if (lr == 0) {
#pragma unroll
    for (int r = 0; r < 4; ++r) sred[wn * 32 + wm * 16 + lq * 4 + r] = s[r];
  }
  __syncthreads();
  if (wn == 0 && lr == 0) {
#pragma unroll
    for (int r = 0; r < 4; ++r) {
      const int row = wm * 16 + lq * 4 + r;
      out[m0 + row] = sred[row] + sred[32 + row] + b2[0];
    }
  }
}

// ================= launch =================
extern "C" void kernel_launch(void* const* d_in, const int* in_sizes, int n_in,
                              void* d_out, int out_size, void* d_ws, size_t ws_size,
                              hipStream_t stream) {
  const float* h0       = (const float*)d_in[0];
  const int*   idx0     = (const int*)  d_in[1];
  const int*   idx1     = (const int*)  d_in[2];
  const float* W_ih1    = (const float*)d_in[3];
  const float* W_hh1    = (const float*)d_in[4];
  const float* b_ih1    = (const float*)d_in[5];
  const float* b_hh1    = (const float*)d_in[6];
  const float* W_self1  = (const float*)d_in[7];
  const float* W_neigh1 = (const float*)d_in[8];
  const float* b_neigh1 = (const float*)d_in[9];
  const float* W_ih2    = (const float*)d_in[10];
  const float* W_hh2    = (const float*)d_in[11];
  const float* b_ih2    = (const float*)d_in[12];
  const float* b_hh2    = (const float*)d_in[13];
  const float* W_self2  = (const float*)d_in[14];
  const float* W_neigh2 = (const float*)d_in[15];
  const float* b_neigh2 = (const float*)d_in[16];
  const float* ln_g     = (const float*)d_in[17];
  const float* ln_b     = (const float*)d_in[18];
  const float* bn_g     = (const float*)d_in[19];
  const float* bn_b     = (const float*)d_in[20];
  const float* bn_mean  = (const float*)d_in[21];
  const float* bn_var   = (const float*)d_in[22];
  const float* W1       = (const float*)d_in[23];
  const float* b1       = (const float*)d_in[24];
  const float* W2       = (const float*)d_in[25];
  const float* b2       = (const float*)d_in[26];
  float* out = (float*)d_out;

  // ---- workspace layout (float units) ----
  float* ws = (float*)d_ws;
  unsigned short* packB1 = (unsigned short*)ws;                   // 262144 f
  unsigned short* packB2 = (unsigned short*)(ws + 262144);        // 262144 f
  unsigned short* packC1 = (unsigned short*)(ws + 524288);        // 65536 f
  unsigned short* packC2 = (unsigned short*)(ws + 589824);        // 65536 f
  unsigned short* packM  = (unsigned short*)(ws + 655360);        // 32768 f
  float* bcat1 = ws + 688128;                                     // 1024
  float* bcat2 = bcat1 + 1024;                                    // 1024
  unsigned short* h0b = (unsigned short*)(bcat2 + 1024);          // 16777216 f
  float* afterh0 = (float*)h0b + 16777216;
  unsigned short* hbA = (unsigned short*)afterh0;                 // 2097152 f
  unsigned short* hbB = (unsigned short*)(afterh0 + 2097152);     // 2097152 f
  float* cbuf = afterh0 + 4194304;                                // 4194304
  unsigned short* h1b = (unsigned short*)(cbuf + 4194304);        // 2097152 f
  unsigned short* h3b = (unsigned short*)(cbuf + 4194304 + 2097152); // 524288 f

  // ---- fused prep (1 dispatch) ----
  prep_kernel<<<9480, 256, 0, stream>>>(
      h0b, h0,
      packB1, W_ih1, W_hh1,
      packB2, W_ih2, W_hh2,
      packC1, W_self1, W_neigh1,
      packC2, W_self2, W_neigh2,
      packM, W1,
      bcat1, b_ih1, b_hh1,
      bcat2, b_ih2, b_hh2);

  // ---- layer 1 LSTM (128-row tiles, per-step, 2-buf LDS) ----
  for (int t = 0; t < PK; ++t) {
    unsigned short* hin  = (t & 1) ? hbA : hbB;
    unsigned short* hout = (t & 1) ? hbB : hbA;
    lstm_step_t<4><<<dim3(PN1 / 128, 8), 256, 0, stream>>>(
        h0b, idx0, t, hin, packB1, bcat1, cbuf, hout, t == 0);
  }
  // final h = hbB (t=7 odd); combine + gelu + LN fused
  combine_ln_kernel<<<PN1 / 32, 256, 0, stream>>>(
      h0b, hbB, packC1, b_neigh1, h1b, ln_g, ln_b,
      nullptr, nullptr, nullptr, nullptr, 0);

  // ---- layer 2 LSTM (64-row tiles, per-step, 2-buf LDS) ----
  for (int t = 0; t < PK; ++t) {
    unsigned short* hin  = (t & 1) ? hbA : hbB;
    unsigned short* hout = (t & 1) ? hbB : hbA;
    lstm_step_t<2><<<dim3(PN2 / 64, 8), 256, 0, stream>>>(
        h1b, idx1, t, hin, packB2, bcat2, cbuf, hout, t == 0);
  }
  combine_ln_kernel<<<PN2 / 32, 256, 0, stream>>>(
      h1b, hbB, packC2, b_neigh2, h3b, ln_g, ln_b,
      bn_mean, bn_var, bn_g, bn_b, 1);
  // MLP + head fused
  mlp_head_kernel<<<PN2 / 32, 256, 0, stream>>>(h3b, packM, b1, W2, b2, out);
}